// Round 4
// baseline (380.544 us; speedup 1.0000x reference)
//
#include <hip/hip_runtime.h>
#include <math.h>

#define TPB 512          // 8 waves/block; 1024 blocks -> 32 waves/CU (full residency)
#define NBLK 1024
#define CCLS 1000

// Wave-wide f32 sum via DPP (VALU pipe only, no DS/lgkmcnt):
// row_shr 1/2/4/8 -> lane15 of each 16-row holds row sum;
// row_bcast:15 (rows 1,3) and row_bcast:31 (rows 2,3) combine -> lane 63 = total.
// readlane(63) broadcasts through an SGPR. Chain = 6 VALU adds + 1 readlane.
__device__ __forceinline__ float wave_sum64(float x) {
  int t;
  t = __builtin_amdgcn_update_dpp(0, __float_as_int(x), 0x111, 0xf, 0xf, true); x += __int_as_float(t); // row_shr:1
  t = __builtin_amdgcn_update_dpp(0, __float_as_int(x), 0x112, 0xf, 0xf, true); x += __int_as_float(t); // row_shr:2
  t = __builtin_amdgcn_update_dpp(0, __float_as_int(x), 0x114, 0xf, 0xf, true); x += __int_as_float(t); // row_shr:4
  t = __builtin_amdgcn_update_dpp(0, __float_as_int(x), 0x118, 0xf, 0xf, true); x += __int_as_float(t); // row_shr:8
  t = __builtin_amdgcn_update_dpp(0, __float_as_int(x), 0x142, 0xa, 0xf, true); x += __int_as_float(t); // row_bcast:15 -> rows 1,3
  t = __builtin_amdgcn_update_dpp(0, __float_as_int(x), 0x143, 0xc, 0xf, true); x += __int_as_float(t); // row_bcast:31 -> rows 2,3
  return __int_as_float(__builtin_amdgcn_readlane(__float_as_int(x), 63));
}

// Stage 1: per-row L2norm + softmax accumulate + fused bincount (-1.0 into the
// same per-class LDS accumulator), then PLAIN stores of the block's 1000 partials
// into a private workspace slice. No global atomics, no fences (the r1/r2
// threadfence/ACQ_REL done-counter cost ~140us on non-coherent 8-XCD L2s).
//
// Software-pipelined: row r+nw's 4 float4 loads are issued BEFORE row r's
// compute chain (~300cy VALU+trans with two DPP reductions), so HBM latency
// (~700cy) hides under compute instead of serializing with it. The a<-n swap
// lets the compiler keep the prefetch in flight across the chain.
//
// One row per wave per iteration: lane l owns float4 chunks {l, 64+l, 128+l, 192+l}
// (last valid if l<58). No max-subtraction: x*inv in [-1,1] after L2 norm ->
// exp in [0.37,2.72], softmax shift-invariant.
__global__ __launch_bounds__(TPB, 8) void mdca_main(const float* __restrict__ X,
                                                    const int* __restrict__ tgt,
                                                    float* __restrict__ part,
                                                    float* __restrict__ out, int B) {
  __shared__ float sacc[1024];
  const int t = threadIdx.x;
  const int lane = t & 63;
  const int wid = blockIdx.x * (TPB / 64) + (t >> 6);
  const int nw = NBLK * (TPB / 64);   // 8192 waves -> 8 rows/wave
  const bool v3 = (lane < 58);

  // zero the scalar output here (kernel-dispatch boundary orders this before
  // mdca_reduce's atomics) -> drops the hipMemsetAsync dispatch entirely.
  if (blockIdx.x == 0 && t == 0) out[0] = 0.f;

  for (int i = t; i < 1024; i += TPB) sacc[i] = 0.f;

  float acc[16];
  #pragma unroll
  for (int i = 0; i < 16; ++i) acc[i] = 0.f;

  const float4 Z = make_float4(0.f, 0.f, 0.f, 0.f);

  // prologue: load first row
  float4 a0 = Z, a1 = Z, a2 = Z, a3 = Z;
  if (wid < B) {
    const float4* b = reinterpret_cast<const float4*>(X + (size_t)wid * CCLS);
    a0 = b[lane]; a1 = b[64 + lane]; a2 = b[128 + lane];
    a3 = v3 ? b[192 + lane] : Z;
  }

  for (int r = wid; r < B; r += nw) {
    // ---- prefetch next row (branchless: re-point at current row when no next;
    // the dead tail-load hits L1/L2) ----
    const int rn = r + nw;
    const float4* bn = reinterpret_cast<const float4*>(
        X + (size_t)(rn < B ? rn : r) * CCLS);
    float4 n0 = bn[lane];
    float4 n1 = bn[64 + lane];
    float4 n2 = bn[128 + lane];
    float4 n3 = v3 ? bn[192 + lane] : Z;

    // ---- compute current row from registers ----
    float ss = a0.x*a0.x + a0.y*a0.y + a0.z*a0.z + a0.w*a0.w
             + a1.x*a1.x + a1.y*a1.y + a1.z*a1.z + a1.w*a1.w
             + a2.x*a2.x + a2.y*a2.y + a2.z*a2.z + a2.w*a2.w
             + a3.x*a3.x + a3.y*a3.y + a3.z*a3.z + a3.w*a3.w;
    ss = wave_sum64(ss);

    const float inv = 1.0f / (sqrtf(ss) + 1e-7f);

    // exp in place (__expf -> v_exp_f32 + mul; known-good codegen)
    a0.x=__expf(a0.x*inv); a0.y=__expf(a0.y*inv); a0.z=__expf(a0.z*inv); a0.w=__expf(a0.w*inv);
    a1.x=__expf(a1.x*inv); a1.y=__expf(a1.y*inv); a1.z=__expf(a1.z*inv); a1.w=__expf(a1.w*inv);
    a2.x=__expf(a2.x*inv); a2.y=__expf(a2.y*inv); a2.z=__expf(a2.z*inv); a2.w=__expf(a2.w*inv);
    a3.x=__expf(a3.x*inv); a3.y=__expf(a3.y*inv); a3.z=__expf(a3.z*inv); a3.w=__expf(a3.w*inv);
    if (!v3) a3 = Z;   // kill exp(0)=1 pollution from inactive chunk-3 lanes

    float es = a0.x+a0.y+a0.z+a0.w + a1.x+a1.y+a1.z+a1.w
             + a2.x+a2.y+a2.z+a2.w + a3.x+a3.y+a3.z+a3.w;
    es = wave_sum64(es);

    const float invS = 1.0f / es;

    acc[0]  += a0.x*invS;  acc[1]  += a0.y*invS;  acc[2]  += a0.z*invS;  acc[3]  += a0.w*invS;
    acc[4]  += a1.x*invS;  acc[5]  += a1.y*invS;  acc[6]  += a1.z*invS;  acc[7]  += a1.w*invS;
    acc[8]  += a2.x*invS;  acc[9]  += a2.y*invS;  acc[10] += a2.z*invS;  acc[11] += a2.w*invS;
    acc[12] += a3.x*invS;  acc[13] += a3.y*invS;  acc[14] += a3.z*invS;  acc[15] += a3.w*invS;

    // ---- advance pipeline ----
    a0 = n0; a1 = n1; a2 = n2; a3 = n3;
  }

  // combine 8 waves in LDS (sacc index == class)
  __syncthreads();   // also guarantees sacc zero-init is complete everywhere
  #pragma unroll
  for (int k = 0; k < 4; ++k)
    #pragma unroll
    for (int j = 0; j < 4; ++j)
      atomicAdd(&sacc[k * 256 + lane * 4 + j], acc[k * 4 + j]);

  // fused bincount: each block owns 64 consecutive targets per stride pass,
  // folded as -1.0 into the same per-class accumulator.
  if (t < 64) {
    for (int i = blockIdx.x * 64 + t; i < B; i += NBLK * 64)
      atomicAdd(&sacc[tgt[i]], -1.0f);
  }
  __syncthreads();

  // plain coalesced stores into this block's private slice -- no atomics, no
  // zero-init needed; cross-XCD visibility via the kernel dispatch boundary.
  float* my = part + (size_t)blockIdx.x * 1024;
  #pragma unroll
  for (int j = 0; j < 2; ++j) {
    int c = t * 2 + j;
    if (c < CCLS) my[c] = sacc[c];
  }
}

// Stage 2: column-reduce the 1024 block-partials, |.|, mean.
// Block b owns classes [4b, 4b+4); thread t float4-sums k = t, t+256, t+512, t+768.
// 250 blocks, ~16MB total from L2/L3, a few us.
__global__ __launch_bounds__(256) void mdca_reduce(const float* __restrict__ part,
                                                   float* __restrict__ out, int B) {
  __shared__ float4 sred[4];
  const int t = threadIdx.x;
  const float* p = part + 4 * blockIdx.x;

  float4 s = make_float4(0.f, 0.f, 0.f, 0.f);
  #pragma unroll
  for (int j = 0; j < 4; ++j) {
    const float4 v = *reinterpret_cast<const float4*>(p + (size_t)(t + 256 * j) * 1024);
    s.x += v.x; s.y += v.y; s.z += v.z; s.w += v.w;
  }
  s.x = wave_sum64(s.x);
  s.y = wave_sum64(s.y);
  s.z = wave_sum64(s.z);
  s.w = wave_sum64(s.w);
  if ((t & 63) == 0) sred[t >> 6] = s;
  __syncthreads();
  if (t == 0) {
    float4 a = sred[0];
    #pragma unroll
    for (int w = 1; w < 4; ++w) {
      a.x += sred[w].x; a.y += sred[w].y; a.z += sred[w].z; a.w += sred[w].w;
    }
    const float invB = 1.0f / (float)B;
    float r = fabsf(a.x * invB) + fabsf(a.y * invB)
            + fabsf(a.z * invB) + fabsf(a.w * invB);
    atomicAdd(out, r / (float)CCLS);   // 250 adds total; out zeroed by mdca_main
  }
}

extern "C" void kernel_launch(void* const* d_in, const int* in_sizes, int n_in,
                              void* d_out, int out_size, void* d_ws, size_t ws_size,
                              hipStream_t stream) {
  const float* X = (const float*)d_in[0];
  const int* tgt = (const int*)d_in[1];
  const int B = in_sizes[1];

  float* part = (float*)d_ws;   // [NBLK * 1024] block-partial arrays (fully overwritten)

  mdca_main<<<NBLK, TPB, 0, stream>>>(X, tgt, part, (float*)d_out, B);
  mdca_reduce<<<250, 256, 0, stream>>>(part, (float*)d_out, B);
}